// Round 12
// baseline (217.559 us; speedup 1.0000x reference)
//
#include <hip/hip_runtime.h>
#include <math.h>
#include <stdint.h>

#define S_N 2048
#define X_N 2048
#define G_N 2
#define F_N 3072

// GEMM tile: 256(M) x 128(N), BK=64, 512 threads = 8 waves.
// 4 wave-positions of 128x64 output; 2 waves per position split the K-tile
// (kh = wave&1 takes k-chunks 0..3 / 4..7), pair-summed via LDS scratch.
#define TM 256
#define TN 128
#define BK 64
#define ITERS (F_N / BK)  // 48
#define NBUF 3            // B triple buffer: no vmcnt(0) drain in main loop

typedef __bf16 bf16;
typedef __bf16 bf16x4 __attribute__((ext_vector_type(4)));
typedef __bf16 bf16x8 __attribute__((ext_vector_type(8)));
typedef float f32x4 __attribute__((ext_vector_type(4)));
typedef int i32x4 __attribute__((ext_vector_type(4)));

__device__ __forceinline__ void gload_lds16(const bf16* g, void* l) {
  __builtin_amdgcn_global_load_lds(
      (const __attribute__((address_space(1))) void*)g,
      (__attribute__((address_space(3))) void*)l, 16, 0, 0);
}

// ---------------- P0: prep, asymmetric factorization (R11, verified) --------
__global__ __launch_bounds__(512) void k_prep(
    const float* __restrict__ samples, const float* __restrict__ xin,
    const float* __restrict__ stdv,
    bf16* __restrict__ U, bf16* __restrict__ V,
    float* __restrict__ A, float* __restrict__ C) {
  __shared__ float rlds[12288];  // [0,6144): rinv g0|g1; [6144,12288): std g0|g1
  __shared__ float redp[16];
  int t = threadIdx.x;
  int bid = blockIdx.x;
  int lane = t & 63, wv = t >> 6;

  for (int i = t; i < 2 * F_N; i += 512) {
    float v = stdv[i];
    rlds[6144 + i] = v;
    rlds[i] = 1.0f / v;
  }

  float sl0 = 0.f, sl1 = 0.f;
  for (int i = t; i < F_N; i += 512) {
    sl0 += logf(stdv[i]);
    sl1 += logf(stdv[F_N + i]);
  }
  for (int o = 32; o; o >>= 1) { sl0 += __shfl_xor(sl0, o); sl1 += __shfl_xor(sl1, o); }
  if (lane == 0) { redp[wv] = sl0; redp[8 + wv] = sl1; }
  __syncthreads();
  float t0 = 0.f, t1 = 0.f;
#pragma unroll
  for (int w2 = 0; w2 < 8; ++w2) { t0 += redp[w2]; t1 += redp[8 + w2]; }
  const float KLOG = -0.5f * (float)F_N * 1.8378770664093453f;
  float c0 = KLOG - t0, c1 = KLOG - t1;

  int l32 = t & 31;
  int rr = bid * 16 + (t >> 5);        // 0..4095
  bool isS = rr < S_N;
  int rx = isS ? rr : rr - S_N;
  const float* src = isS ? samples + (size_t)rx * F_N : xin + (size_t)rx * F_N;

  if (isS) {
    bf16* d = U + (size_t)rx * F_N;
    float a0 = 0.f, a1 = 0.f;
#pragma unroll 4
    for (int k = 0; k < 24; ++k) {
      int c4 = l32 + k * 32;
      float4 sv = ((const float4*)src)[c4];
      float4 r0 = ((const float4*)rlds)[c4];
      float4 r1 = ((const float4*)rlds)[768 + c4];
      bf16x4 b;
      b[0] = (bf16)sv.x; b[1] = (bf16)sv.y; b[2] = (bf16)sv.z; b[3] = (bf16)sv.w;
      ((bf16x4*)d)[c4] = b;
      float f0 = (float)b[0], f1 = (float)b[1], f2 = (float)b[2], f3 = (float)b[3];
      a0 += f0 * f0 * (r0.x * r0.x) + f1 * f1 * (r0.y * r0.y)
          + f2 * f2 * (r0.z * r0.z) + f3 * f3 * (r0.w * r0.w);
      a1 += f0 * f0 * (r1.x * r1.x) + f1 * f1 * (r1.y * r1.y)
          + f2 * f2 * (r1.z * r1.z) + f3 * f3 * (r1.w * r1.w);
    }
    for (int o = 16; o; o >>= 1) { a0 += __shfl_xor(a0, o); a1 += __shfl_xor(a1, o); }
    if (l32 == 0) { A[rx] = a0 - 2.f * c0; A[S_N + rx] = a1 - 2.f * c1; }
  } else {
    bf16* d0 = V + (size_t)rx * F_N;
    bf16* d1 = V + ((size_t)X_N + rx) * F_N;
    const float* slds = rlds + 6144;
    float q0 = 0.f, q1 = 0.f;
#pragma unroll 4
    for (int k = 0; k < 24; ++k) {
      int c4 = l32 + k * 32;
      float4 xv = ((const float4*)src)[c4];
      float4 r0 = ((const float4*)rlds)[c4];
      float4 r1 = ((const float4*)rlds)[768 + c4];
      float4 s0 = ((const float4*)slds)[c4];
      float4 s1 = ((const float4*)slds)[768 + c4];
      bf16x4 y0, y1;
      y0[0] = (bf16)(xv.x * r0.x * r0.x); y0[1] = (bf16)(xv.y * r0.y * r0.y);
      y0[2] = (bf16)(xv.z * r0.z * r0.z); y0[3] = (bf16)(xv.w * r0.w * r0.w);
      y1[0] = (bf16)(xv.x * r1.x * r1.x); y1[1] = (bf16)(xv.y * r1.y * r1.y);
      y1[2] = (bf16)(xv.z * r1.z * r1.z); y1[3] = (bf16)(xv.w * r1.w * r1.w);
      ((bf16x4*)d0)[c4] = y0;
      ((bf16x4*)d1)[c4] = y1;
      float g0 = (float)y0[0] * s0.x, g1 = (float)y0[1] * s0.y;
      float g2 = (float)y0[2] * s0.z, g3 = (float)y0[3] * s0.w;
      q0 += g0 * g0 + g1 * g1 + g2 * g2 + g3 * g3;
      float h0 = (float)y1[0] * s1.x, h1 = (float)y1[1] * s1.y;
      float h2 = (float)y1[2] * s1.z, h3 = (float)y1[3] * s1.w;
      q1 += h0 * h0 + h1 * h1 + h2 * h2 + h3 * h3;
    }
    for (int o = 16; o; o >>= 1) { q0 += __shfl_xor(q0, o); q1 += __shfl_xor(q1, o); }
    if (l32 == 0) { C[rx] = q0; C[X_N + rx] = q1; }
  }
}

// ---------------- P1: logits = u v_g^T - 0.5*(A'+C) -------------------------
// R12: A fragments stream global->REGISTERS (no LDS for A). Deletes 64KB LDS
// reads + 32KB DMA writes per K-tile (DS drops 144->48KB ~= 480cy << MFMA
// 1242cy). A-frag addresses are plain row-major slices (no swizzle): lane
// (r,q) loads U[bm+wm*128+mi*16+r][it*64+kh*32+q*8 ..+8) = 16B, prefetched
// one K-tile ahead into ping-pong reg sets (afA/afB).
// vmcnt ledger: per iter issue {B-DMA(it+2) x2, A-loads(it+1) x12}. MFMA(it)
// auto-waits A(it) (compiler reg-dep), which is YOUNGER than B(it+1)-DMA =>
// B(it+1) retired before the barrier; explicit vmcnt(14) documents this.
// B staging/swizzle/NBUF=3/epilogue byte-identical to R11. Numerics identical.
__global__ __launch_bounds__(512, 2) void k_gemm(const bf16* __restrict__ U, const bf16* __restrict__ V,
                                                 const float* __restrict__ A, const float* __restrict__ C,
                                                 float* __restrict__ logits) {
  // 128 KiB: [0, 3072) i32x4 = B staging (3 bufs x 1024 slots);
  // whole array reused as 8x16KB epilogue scratch.
  __shared__ i32x4 lds[8192];
  i32x4* ldsB = lds;

  int t = threadIdx.x;
  int g = blockIdx.z;
  int bm = blockIdx.y * TM;
  int bn = blockIdx.x * TN;

  const bf16* Vb = V + ((size_t)g * X_N + bn) * F_N;

  int wave = t >> 6, lane = t & 63;
  int pos = wave >> 1;
  int kh = wave & 1;
  int wm = pos >> 1;
  int wn = pos & 1;
  int r = lane & 15, q = lane >> 4;
  int fr = (r >> 1) & 7;
  int ck = (kh * 4 + q) ^ fr;          // B LDS read swizzle (unchanged)
  int bbase = (wn * 64 + r) * 8;

  // A fragment base: row = bm + wm*128 + r (+ mi*16), col = kh*32 + q*8 (+ it*64)
  const bf16* gAr = U + (size_t)(bm + wm * 128 + r) * F_N + kh * 32 + q * 8;

  // B staging (unchanged): slot s = t + j*512, global chunk (s>>3, (s&7)^((s>>4)&7))
  int row0 = t >> 3;
  int gcc = (t & 7) ^ ((t >> 4) & 7);
  const bf16* gB[2];
#pragma unroll
  for (int j = 0; j < 2; ++j) gB[j] = Vb + (size_t)(row0 + j * 64) * F_N + gcc * 8;

  f32x4 acc[8][4] = {};
  bf16x8 afA[8], afB[8], bfr[4];

  // prologue: B(0)->buf0, B(1)->buf1 (DMA); A(0)->afA (regs)
  gload_lds16(gB[0], &ldsB[0 * 1024 + t]);
  gload_lds16(gB[1], &ldsB[0 * 1024 + t + 512]);
  gload_lds16(gB[0] + BK, &ldsB[1 * 1024 + t]);
  gload_lds16(gB[1] + BK, &ldsB[1 * 1024 + t + 512]);
#pragma unroll
  for (int mi = 0; mi < 8; ++mi)
    afA[mi] = *(const bf16x8*)(gAr + (size_t)mi * 16 * F_N);
  asm volatile("s_waitcnt vmcnt(14)" ::: "memory");  // B(0) landed (12 A + 2 B1 remain)
  __builtin_amdgcn_s_barrier();                      // ...for ALL waves
  __builtin_amdgcn_sched_barrier(0);
#pragma unroll
  for (int ni = 0; ni < 4; ++ni)
    bfr[ni] = __builtin_bit_cast(bf16x8, ldsB[bbase + ni * 128 + ck]);

#define ATILE(IT, A_CUR, A_NXT)                                                  \
  {                                                                              \
    int k2 = (IT) + 2;                                                           \
    int pkB = (k2 < ITERS ? k2 : 0) * BK;  /* clamped: uniform vmcnt in tail */  \
    int k1 = (IT) + 1;                                                           \
    int pkA = (k1 < ITERS ? k1 : 0) * BK;                                        \
    int stg = ((IT) + 2) % 3;                                                    \
    int nxt = ((IT) + 1) % 3;                                                    \
    /* issue: 2 B-DMA (tile IT+2), then 12 A reg-loads (tile IT+1) */            \
    gload_lds16(gB[0] + pkB, &ldsB[stg * 1024 + t]);                             \
    gload_lds16(gB[1] + pkB, &ldsB[stg * 1024 + t + 512]);                       \
    _Pragma("unroll")                                                            \
    for (int mi = 0; mi < 8; ++mi)                                               \
      A_NXT[mi] = *(const bf16x8*)(gAr + (size_t)mi * 16 * F_N + pkA);           \
    /* MFMA burst: A_CUR regs (auto-vmcnt retires B(IT+1), older) + bfr */       \
    __builtin_amdgcn_s_setprio(1);                                               \
    _Pragma("unroll")                                                            \
    for (int ni = 0; ni < 4; ++ni)                                               \
      _Pragma("unroll")                                                          \
      for (int mi = 0; mi < 8; ++mi)                                             \
        acc[mi][ni] = __builtin_amdgcn_mfma_f32_16x16x32_bf16(A_CUR[mi], bfr[ni], acc[mi][ni], 0, 0, 0); \
    __builtin_amdgcn_s_setprio(0);                                               \
    /* outstanding <= B(IT+2)2 + A(IT+1)12 = 14; B(IT+1) guaranteed landed */    \
    asm volatile("s_waitcnt vmcnt(14)" ::: "memory");                            \
    __builtin_amdgcn_s_barrier();                                                \
    __builtin_amdgcn_sched_barrier(0);                                           \
    _Pragma("unroll")                                                            \
    for (int ni = 0; ni < 4; ++ni)                                               \
      bfr[ni] = __builtin_bit_cast(bf16x8, ldsB[nxt * 1024 + bbase + ni * 128 + ck]); \
  }

  for (int it0 = 0; it0 < ITERS; it0 += 2) {
    ATILE(it0,     afA, afB)
    ATILE(it0 + 1, afB, afA)
  }
#undef ATILE

  // ---- epilogue: drain everything before LDS scratch reuse
  asm volatile("s_waitcnt vmcnt(0) lgkmcnt(0)" ::: "memory");
  __builtin_amdgcn_s_barrier();

  // pair half-exchange: wave w and w^1 share one 128x64 output.
  f32x4* scr = (f32x4*)lds;
  {
    f32x4* mw = scr + wave * 1024;
    if (kh == 0) {
#pragma unroll
      for (int mi = 0; mi < 8; ++mi)
#pragma unroll
        for (int nl = 0; nl < 2; ++nl)
          mw[(mi * 2 + nl) * 64 + lane] = acc[mi][2 + nl];
    } else {
#pragma unroll
      for (int mi = 0; mi < 8; ++mi)
#pragma unroll
        for (int nl = 0; nl < 2; ++nl)
          mw[(mi * 2 + nl) * 64 + lane] = acc[mi][nl];
    }
  }
  __syncthreads();
  {
    const f32x4* pw = scr + (wave ^ 1) * 1024;
    if (kh == 0) {
#pragma unroll
      for (int mi = 0; mi < 8; ++mi)
#pragma unroll
        for (int nl = 0; nl < 2; ++nl)
          acc[mi][nl] += pw[(mi * 2 + nl) * 64 + lane];
    } else {
#pragma unroll
      for (int mi = 0; mi < 8; ++mi)
#pragma unroll
        for (int nl = 0; nl < 2; ++nl)
          acc[mi][2 + nl] += pw[(mi * 2 + nl) * 64 + lane];
    }
  }

  const float* Ap = A + (size_t)g * S_N + bm + wm * 128;
  const float* Cp = C + (size_t)g * X_N + bn + wn * 64 + kh * 32;
  float cv[2];
  cv[0] = Cp[r]; cv[1] = Cp[16 + r];
#pragma unroll
  for (int mi = 0; mi < 8; ++mi) {
#pragma unroll
    for (int i = 0; i < 4; ++i) {
      int rowl = mi * 16 + q * 4 + i;
      float av = Ap[rowl];
      float* orow = logits + ((size_t)g * S_N + bm + wm * 128 + rowl) * X_N + bn + wn * 64 + kh * 32;
      if (kh == 0) {
        orow[r]      = acc[mi][0][i] - 0.5f * (av + cv[0]);
        orow[16 + r] = acc[mi][1][i] - 0.5f * (av + cv[1]);
      } else {
        orow[r]      = acc[mi][2][i] - 0.5f * (av + cv[0]);
        orow[16 + r] = acc[mi][3][i] - 0.5f * (av + cv[1]);
      }
    }
  }
}

// ---------------- P2: out[s] = LSE over (g,x) of logits - log(X*G) ----------
__global__ void k_lse(const float* __restrict__ logits, float* __restrict__ out) {
  int s = blockIdx.x, t = threadIdx.x;
  const float4* p0 = (const float4*)(logits + (size_t)s * X_N);
  const float4* p1 = (const float4*)(logits + ((size_t)S_N + s) * X_N);
  float4 v[4];
  v[0] = p0[t]; v[1] = p0[t + 256];
  v[2] = p1[t]; v[3] = p1[t + 256];

  float m = v[0].x;
#pragma unroll
  for (int j = 0; j < 4; ++j) {
    m = fmaxf(m, v[j].x); m = fmaxf(m, v[j].y);
    m = fmaxf(m, v[j].z); m = fmaxf(m, v[j].w);
  }
  for (int o = 32; o; o >>= 1) m = fmaxf(m, __shfl_xor(m, o));
  __shared__ float redm[4];
  __shared__ float reds[4];
  int w = t >> 6, l = t & 63;
  if (l == 0) redm[w] = m;
  __syncthreads();
  m = fmaxf(fmaxf(redm[0], redm[1]), fmaxf(redm[2], redm[3]));

  float sum = 0.f;
#pragma unroll
  for (int j = 0; j < 4; ++j) {
    sum += expf(v[j].x - m) + expf(v[j].y - m) + expf(v[j].z - m) + expf(v[j].w - m);
  }
  for (int o = 32; o; o >>= 1) sum += __shfl_xor(sum, o);
  if (l == 0) reds[w] = sum;
  __syncthreads();
  if (t == 0) {
    float tot = reds[0] + reds[1] + reds[2] + reds[3];
    out[s] = m + logf(tot) - 8.317766166719343f;  // log(4096)
  }
}

extern "C" void kernel_launch(void* const* d_in, const int* in_sizes, int n_in,
                              void* d_out, int out_size, void* d_ws, size_t ws_size,
                              hipStream_t stream) {
  const float* samples = (const float*)d_in[0];  // [S, F] fp32
  const float* xin     = (const float*)d_in[1];  // [X, F] fp32
  const float* stdv    = (const float*)d_in[2];  // [G, F] fp32
  float* out = (float*)d_out;                    // [S] fp32

  char* ws = (char*)d_ws;
  size_t off = 0;
  bf16* U = (bf16*)(ws + off);        off += (size_t)S_N * F_N * 2;          // 12.6 MB (g-independent)
  bf16* V = (bf16*)(ws + off);        off += (size_t)G_N * X_N * F_N * 2;    // 25.2 MB
  float* logits = (float*)(ws + off); off += (size_t)G_N * S_N * X_N * 4;    // 33.6 MB
  float* A = (float*)(ws + off);      off += (size_t)G_N * S_N * 4;
  float* C = (float*)(ws + off);      off += (size_t)G_N * X_N * 4;

  k_prep<<<dim3(256), dim3(512), 0, stream>>>(samples, xin, stdv, U, V, A, C);
  k_gemm<<<dim3(X_N / TN, S_N / TM, G_N), dim3(512), 0, stream>>>(U, V, A, C, logits);
  k_lse<<<dim3(S_N), dim3(256), 0, stream>>>(logits, out);
}

// Round 13
// 163.382 us; speedup vs baseline: 1.3316x; 1.3316x over previous
//
#include <hip/hip_runtime.h>
#include <math.h>
#include <stdint.h>

#define S_N 2048
#define X_N 2048
#define G_N 2
#define F_N 3072

// R13 GEMM geometry: tile 128x128, 256 thr = 4 waves (2x2, 64x64 each, no
// kh-split), BK=32, NBUF=3 -> 48 KiB LDS -> grid 512 = 2 blocks/CU.
// Per-CU DS/MFMA totals identical to R11; the delta is two independently
// drifting blocks per CU so one block's MFMA hides the other's DS burst
// (m114: MFMA and memory pipes co-schedule across waves).
#define TM 128
#define TN 128
#define BK 32
#define ITERS (F_N / BK)  // 96
#define NBUF 3

typedef __bf16 bf16;
typedef __bf16 bf16x4 __attribute__((ext_vector_type(4)));
typedef __bf16 bf16x8 __attribute__((ext_vector_type(8)));
typedef float f32x4 __attribute__((ext_vector_type(4)));
typedef int i32x4 __attribute__((ext_vector_type(4)));

__device__ __forceinline__ void gload_lds16(const bf16* g, void* l) {
  __builtin_amdgcn_global_load_lds(
      (const __attribute__((address_space(1))) void*)g,
      (__attribute__((address_space(3))) void*)l, 16, 0, 0);
}

// ---------------- P0: prep, asymmetric factorization (R11, verified) --------
__global__ __launch_bounds__(512) void k_prep(
    const float* __restrict__ samples, const float* __restrict__ xin,
    const float* __restrict__ stdv,
    bf16* __restrict__ U, bf16* __restrict__ V,
    float* __restrict__ A, float* __restrict__ C) {
  __shared__ float rlds[12288];  // [0,6144): rinv g0|g1; [6144,12288): std g0|g1
  __shared__ float redp[16];
  int t = threadIdx.x;
  int bid = blockIdx.x;
  int lane = t & 63, wv = t >> 6;

  for (int i = t; i < 2 * F_N; i += 512) {
    float v = stdv[i];
    rlds[6144 + i] = v;
    rlds[i] = 1.0f / v;
  }

  float sl0 = 0.f, sl1 = 0.f;
  for (int i = t; i < F_N; i += 512) {
    sl0 += logf(stdv[i]);
    sl1 += logf(stdv[F_N + i]);
  }
  for (int o = 32; o; o >>= 1) { sl0 += __shfl_xor(sl0, o); sl1 += __shfl_xor(sl1, o); }
  if (lane == 0) { redp[wv] = sl0; redp[8 + wv] = sl1; }
  __syncthreads();
  float t0 = 0.f, t1 = 0.f;
#pragma unroll
  for (int w2 = 0; w2 < 8; ++w2) { t0 += redp[w2]; t1 += redp[8 + w2]; }
  const float KLOG = -0.5f * (float)F_N * 1.8378770664093453f;
  float c0 = KLOG - t0, c1 = KLOG - t1;

  int l32 = t & 31;
  int rr = bid * 16 + (t >> 5);        // 0..4095
  bool isS = rr < S_N;
  int rx = isS ? rr : rr - S_N;
  const float* src = isS ? samples + (size_t)rx * F_N : xin + (size_t)rx * F_N;

  if (isS) {
    bf16* d = U + (size_t)rx * F_N;
    float a0 = 0.f, a1 = 0.f;
#pragma unroll 4
    for (int k = 0; k < 24; ++k) {
      int c4 = l32 + k * 32;
      float4 sv = ((const float4*)src)[c4];
      float4 r0 = ((const float4*)rlds)[c4];
      float4 r1 = ((const float4*)rlds)[768 + c4];
      bf16x4 b;
      b[0] = (bf16)sv.x; b[1] = (bf16)sv.y; b[2] = (bf16)sv.z; b[3] = (bf16)sv.w;
      ((bf16x4*)d)[c4] = b;
      float f0 = (float)b[0], f1 = (float)b[1], f2 = (float)b[2], f3 = (float)b[3];
      a0 += f0 * f0 * (r0.x * r0.x) + f1 * f1 * (r0.y * r0.y)
          + f2 * f2 * (r0.z * r0.z) + f3 * f3 * (r0.w * r0.w);
      a1 += f0 * f0 * (r1.x * r1.x) + f1 * f1 * (r1.y * r1.y)
          + f2 * f2 * (r1.z * r1.z) + f3 * f3 * (r1.w * r1.w);
    }
    for (int o = 16; o; o >>= 1) { a0 += __shfl_xor(a0, o); a1 += __shfl_xor(a1, o); }
    if (l32 == 0) { A[rx] = a0 - 2.f * c0; A[S_N + rx] = a1 - 2.f * c1; }
  } else {
    bf16* d0 = V + (size_t)rx * F_N;
    bf16* d1 = V + ((size_t)X_N + rx) * F_N;
    const float* slds = rlds + 6144;
    float q0 = 0.f, q1 = 0.f;
#pragma unroll 4
    for (int k = 0; k < 24; ++k) {
      int c4 = l32 + k * 32;
      float4 xv = ((const float4*)src)[c4];
      float4 r0 = ((const float4*)rlds)[c4];
      float4 r1 = ((const float4*)rlds)[768 + c4];
      float4 s0 = ((const float4*)slds)[c4];
      float4 s1 = ((const float4*)slds)[768 + c4];
      bf16x4 y0, y1;
      y0[0] = (bf16)(xv.x * r0.x * r0.x); y0[1] = (bf16)(xv.y * r0.y * r0.y);
      y0[2] = (bf16)(xv.z * r0.z * r0.z); y0[3] = (bf16)(xv.w * r0.w * r0.w);
      y1[0] = (bf16)(xv.x * r1.x * r1.x); y1[1] = (bf16)(xv.y * r1.y * r1.y);
      y1[2] = (bf16)(xv.z * r1.z * r1.z); y1[3] = (bf16)(xv.w * r1.w * r1.w);
      ((bf16x4*)d0)[c4] = y0;
      ((bf16x4*)d1)[c4] = y1;
      float g0 = (float)y0[0] * s0.x, g1 = (float)y0[1] * s0.y;
      float g2 = (float)y0[2] * s0.z, g3 = (float)y0[3] * s0.w;
      q0 += g0 * g0 + g1 * g1 + g2 * g2 + g3 * g3;
      float h0 = (float)y1[0] * s1.x, h1 = (float)y1[1] * s1.y;
      float h2 = (float)y1[2] * s1.z, h3 = (float)y1[3] * s1.w;
      q1 += h0 * h0 + h1 * h1 + h2 * h2 + h3 * h3;
    }
    for (int o = 16; o; o >>= 1) { q0 += __shfl_xor(q0, o); q1 += __shfl_xor(q1, o); }
    if (l32 == 0) { C[rx] = q0; C[X_N + rx] = q1; }
  }
}

// ---------------- P1: logits = u v_g^T - 0.5*(A'[g,s]+C[g,x]) ---------------
// Loop = R11's verified rhythm scaled to BK=32: per iter {4 gloads(it+2),
// 16 MFMA (ni-outer), vmcnt(4), barrier, 12 frag reads (bfr first)}.
// Swizzle for 64B rows (32 bf16): LDS slot (row, c) holds global chunk
// c ^ ((row>>1)&3); staged via inverse-swizzled global source (linear LDS
// dest, rule 21); read addr uses the same XOR. Tail pk clamped to 0 keeps
// vmcnt math uniform (loads land in stg buffer, never read).
__global__ __launch_bounds__(256, 2) void k_gemm(const bf16* __restrict__ U, const bf16* __restrict__ V,
                                                 const float* __restrict__ A, const float* __restrict__ C,
                                                 float* __restrict__ logits) {
  // per buf: A 512 slots (128 rows x 4 chunks), B 512 slots. 3 bufs = 48 KiB.
  __shared__ i32x4 ldsA[NBUF * 512];
  __shared__ i32x4 ldsB[NBUF * 512];

  int t = threadIdx.x;
  int g = blockIdx.z;
  int bm = blockIdx.y * TM;
  int bn = blockIdx.x * TN;

  const bf16* Ub = U + (size_t)bm * F_N;                 // U is g-independent
  const bf16* Vb = V + ((size_t)g * X_N + bn) * F_N;

  int wave = t >> 6, lane = t & 63;
  int wm = wave & 1, wn = wave >> 1;   // 2x2 waves, 64x64 each
  int r = lane & 15, q = lane >> 4;
  int cs = (r >> 1) & 3;               // (row>>1)&3 with row=base16+r (base%16==0)
  int ck = q ^ cs;                     // swizzled chunk for this lane's rows
  // frag slot = (base + r)*4 + ck; bases: A row base = wm*64+mi*16, B = wn*64+ni*16
  int abase = (wm * 64 + r) * 4 + ck;
  int bbase = (wn * 64 + r) * 4 + ck;

  // Staging: 512 slots/tile, 2 per thread (t, t+256). Slot s: row=s>>2, cc=s&3,
  // global chunk gcc = (s&3)^((s>>3)&3); j-invariant for +256 (256>>3=32, &3=0).
  int row0 = t >> 2;                   // 0..63
  int gcc = (t & 3) ^ ((t >> 3) & 3);
  const bf16* gA[2];
  const bf16* gB[2];
#pragma unroll
  for (int j = 0; j < 2; ++j) {
    gA[j] = Ub + (size_t)(row0 + j * 64) * F_N + gcc * 8;
    gB[j] = Vb + (size_t)(row0 + j * 64) * F_N + gcc * 8;
  }

  f32x4 acc[4][4] = {};
  bf16x8 af[4], bfr[4];

  // prologue: tile0 -> buf0, tile1 -> buf1 (4 loads each)
#pragma unroll
  for (int j = 0; j < 2; ++j) {
    gload_lds16(gA[j], &ldsA[0 * 512 + t + j * 256]);
    gload_lds16(gB[j], &ldsB[0 * 512 + t + j * 256]);
  }
#pragma unroll
  for (int j = 0; j < 2; ++j) {
    gload_lds16(gA[j] + BK, &ldsA[1 * 512 + t + j * 256]);
    gload_lds16(gB[j] + BK, &ldsB[1 * 512 + t + j * 256]);
  }
  asm volatile("s_waitcnt vmcnt(4)" ::: "memory");  // tile0 landed (per-wave)
  __builtin_amdgcn_s_barrier();                      // ...for ALL waves
  __builtin_amdgcn_sched_barrier(0);
#pragma unroll
  for (int ni = 0; ni < 4; ++ni)
    bfr[ni] = __builtin_bit_cast(bf16x8, ldsB[bbase + ni * 64]);
#pragma unroll
  for (int mi = 0; mi < 4; ++mi)
    af[mi] = __builtin_bit_cast(bf16x8, ldsA[abase + mi * 64]);

  int cur = 0;
  for (int it = 0; it < ITERS; ++it) {
    int k2 = it + 2;
    int pk = (k2 < ITERS ? k2 : 0) * BK;  // clamped: uniform vmcnt in tail
    int stg = (cur >= 1) ? cur - 1 : 2;   // (cur+2)%3
    int nxt = (cur == 2) ? 0 : cur + 1;
    const i32x4* LAn = ldsA + nxt * 512;
    const i32x4* LBn = ldsB + nxt * 512;

    // issue tile it+2 DMA (4 loads) under the MFMA burst
    gload_lds16(gA[0] + pk, &ldsA[stg * 512 + t]);
    gload_lds16(gA[1] + pk, &ldsA[stg * 512 + t + 256]);
    gload_lds16(gB[0] + pk, &ldsB[stg * 512 + t]);
    gload_lds16(gB[1] + pk, &ldsB[stg * 512 + t + 256]);

    // K-tile MFMA burst (frags pre-read last iteration)
    __builtin_amdgcn_s_setprio(1);
#pragma unroll
    for (int ni = 0; ni < 4; ++ni)
#pragma unroll
      for (int mi = 0; mi < 4; ++mi)
        acc[mi][ni] = __builtin_amdgcn_mfma_f32_16x16x32_bf16(af[mi], bfr[ni], acc[mi][ni], 0, 0, 0);
    __builtin_amdgcn_s_setprio(0);

    // outstanding: tile it+1 (4, oldest) + it+2 (4) -> it+1 landed
    asm volatile("s_waitcnt vmcnt(4)" ::: "memory");
    __builtin_amdgcn_s_barrier();
    __builtin_amdgcn_sched_barrier(0);
#pragma unroll
    for (int ni = 0; ni < 4; ++ni)
      bfr[ni] = __builtin_bit_cast(bf16x8, LBn[bbase + ni * 64]);
#pragma unroll
    for (int mi = 0; mi < 4; ++mi)
      af[mi] = __builtin_bit_cast(bf16x8, LAn[abase + mi * 64]);

    cur = nxt;
  }

  // drain tail DMA before exit (LDS not reused; cheap safety)
  asm volatile("s_waitcnt vmcnt(0) lgkmcnt(0)" ::: "memory");

  // Epilogue: direct store, no pair-exchange (each wave owns 64x64).
  // C/D layout: col=lane&15, row=(lane>>4)*4+reg.
  const float* Ap = A + (size_t)g * S_N + bm + wm * 64;
  const float* Cp = C + (size_t)g * X_N + bn + wn * 64;
  float cv[4];
#pragma unroll
  for (int ni = 0; ni < 4; ++ni) cv[ni] = Cp[ni * 16 + r];
#pragma unroll
  for (int mi = 0; mi < 4; ++mi) {
#pragma unroll
    for (int i = 0; i < 4; ++i) {
      int rowl = mi * 16 + q * 4 + i;
      float av = Ap[rowl];
      float* orow = logits + ((size_t)g * S_N + bm + wm * 64 + rowl) * X_N + bn + wn * 64;
#pragma unroll
      for (int ni = 0; ni < 4; ++ni)
        orow[ni * 16 + r] = acc[mi][ni][i] - 0.5f * (av + cv[ni]);
    }
  }
}

// ---------------- P2: out[s] = LSE over (g,x) of logits - log(X*G) ----------
__global__ void k_lse(const float* __restrict__ logits, float* __restrict__ out) {
  int s = blockIdx.x, t = threadIdx.x;
  const float4* p0 = (const float4*)(logits + (size_t)s * X_N);
  const float4* p1 = (const float4*)(logits + ((size_t)S_N + s) * X_N);
  float4 v[4];
  v[0] = p0[t]; v[1] = p0[t + 256];
  v[2] = p1[t]; v[3] = p1[t + 256];

  float m = v[0].x;
#pragma unroll
  for (int j = 0; j < 4; ++j) {
    m = fmaxf(m, v[j].x); m = fmaxf(m, v[j].y);
    m = fmaxf(m, v[j].z); m = fmaxf(m, v[j].w);
  }
  for (int o = 32; o; o >>= 1) m = fmaxf(m, __shfl_xor(m, o));
  __shared__ float redm[4];
  __shared__ float reds[4];
  int w = t >> 6, l = t & 63;
  if (l == 0) redm[w] = m;
  __syncthreads();
  m = fmaxf(fmaxf(redm[0], redm[1]), fmaxf(redm[2], redm[3]));

  float sum = 0.f;
#pragma unroll
  for (int j = 0; j < 4; ++j) {
    sum += expf(v[j].x - m) + expf(v[j].y - m) + expf(v[j].z - m) + expf(v[j].w - m);
  }
  for (int o = 32; o; o >>= 1) sum += __shfl_xor(sum, o);
  if (l == 0) reds[w] = sum;
  __syncthreads();
  if (t == 0) {
    float tot = reds[0] + reds[1] + reds[2] + reds[3];
    out[s] = m + logf(tot) - 8.317766166719343f;  // log(4096)
  }
}

extern "C" void kernel_launch(void* const* d_in, const int* in_sizes, int n_in,
                              void* d_out, int out_size, void* d_ws, size_t ws_size,
                              hipStream_t stream) {
  const float* samples = (const float*)d_in[0];  // [S, F] fp32
  const float* xin     = (const float*)d_in[1];  // [X, F] fp32
  const float* stdv    = (const float*)d_in[2];  // [G, F] fp32
  float* out = (float*)d_out;                    // [S] fp32

  char* ws = (char*)d_ws;
  size_t off = 0;
  bf16* U = (bf16*)(ws + off);        off += (size_t)S_N * F_N * 2;          // 12.6 MB (g-independent)
  bf16* V = (bf16*)(ws + off);        off += (size_t)G_N * X_N * F_N * 2;    // 25.2 MB
  float* logits = (float*)(ws + off); off += (size_t)G_N * S_N * X_N * 4;    // 33.6 MB
  float* A = (float*)(ws + off);      off += (size_t)G_N * S_N * 4;
  float* C = (float*)(ws + off);      off += (size_t)G_N * X_N * 4;

  k_prep<<<dim3(256), dim3(512), 0, stream>>>(samples, xin, stdv, U, V, A, C);
  k_gemm<<<dim3(X_N / TN, S_N / TM, G_N), dim3(256), 0, stream>>>(U, V, A, C, logits);
  k_lse<<<dim3(S_N), dim3(256), 0, stream>>>(logits, out);
}

// Round 14
// 154.288 us; speedup vs baseline: 1.4101x; 1.0589x over previous
//
#include <hip/hip_runtime.h>
#include <math.h>
#include <stdint.h>

#define S_N 2048
#define X_N 2048
#define G_N 2
#define F_N 3072

// GEMM tile: 256(M) x 128(N), BK=64, 512 threads = 8 waves.
// 4 wave-positions of 128x64 output; 2 waves per position split the K-tile
// (kh = wave&1 takes k-chunks 0..3 / 4..7), pair-summed via LDS scratch.
// R14 = R11 verbatim (measured best: gemm 53.7us, wall 152.2us) + wave-per-row
// k_lse. The R12 (A-in-regs) and R13 (BK=32 2-blocks/CU) excursions both
// regressed and are reverted.
#define TM 256
#define TN 128
#define BK 64
#define ITERS (F_N / BK)  // 48
#define NBUF 3            // triple buffer: no vmcnt(0) drain in main loop

typedef __bf16 bf16;
typedef __bf16 bf16x4 __attribute__((ext_vector_type(4)));
typedef __bf16 bf16x8 __attribute__((ext_vector_type(8)));
typedef float f32x4 __attribute__((ext_vector_type(4)));
typedef int i32x4 __attribute__((ext_vector_type(4)));

__device__ __forceinline__ void gload_lds16(const bf16* g, void* l) {
  __builtin_amdgcn_global_load_lds(
      (const __attribute__((address_space(1))) void*)g,
      (__attribute__((address_space(3))) void*)l, 16, 0, 0);
}

// ---------------- P0: prep, asymmetric factorization (R11, verified) --------
// u·v_g = sum_f s_f * (x_f * w_gf): U = bf16(s) is g-INDEPENDENT (12.6 MB),
// V_g = bf16(x*w_g). Matching norms keep the quadratic consistent:
//   A'[g,s] = sum s~^2 w_g - 2*constg[g];  C[g,x] = sum (y^*std_g)^2.
__global__ __launch_bounds__(512) void k_prep(
    const float* __restrict__ samples, const float* __restrict__ xin,
    const float* __restrict__ stdv,
    bf16* __restrict__ U, bf16* __restrict__ V,
    float* __restrict__ A, float* __restrict__ C) {
  __shared__ float rlds[12288];  // [0,6144): rinv g0|g1; [6144,12288): std g0|g1
  __shared__ float redp[16];
  int t = threadIdx.x;
  int bid = blockIdx.x;
  int lane = t & 63, wv = t >> 6;

  for (int i = t; i < 2 * F_N; i += 512) {
    float v = stdv[i];
    rlds[6144 + i] = v;
    rlds[i] = 1.0f / v;
  }

  float sl0 = 0.f, sl1 = 0.f;
  for (int i = t; i < F_N; i += 512) {
    sl0 += logf(stdv[i]);
    sl1 += logf(stdv[F_N + i]);
  }
  for (int o = 32; o; o >>= 1) { sl0 += __shfl_xor(sl0, o); sl1 += __shfl_xor(sl1, o); }
  if (lane == 0) { redp[wv] = sl0; redp[8 + wv] = sl1; }
  __syncthreads();
  float t0 = 0.f, t1 = 0.f;
#pragma unroll
  for (int w2 = 0; w2 < 8; ++w2) { t0 += redp[w2]; t1 += redp[8 + w2]; }
  const float KLOG = -0.5f * (float)F_N * 1.8378770664093453f;
  float c0 = KLOG - t0, c1 = KLOG - t1;

  int l32 = t & 31;
  int rr = bid * 16 + (t >> 5);        // 0..4095
  bool isS = rr < S_N;
  int rx = isS ? rr : rr - S_N;
  const float* src = isS ? samples + (size_t)rx * F_N : xin + (size_t)rx * F_N;

  if (isS) {
    bf16* d = U + (size_t)rx * F_N;
    float a0 = 0.f, a1 = 0.f;
#pragma unroll 4
    for (int k = 0; k < 24; ++k) {
      int c4 = l32 + k * 32;
      float4 sv = ((const float4*)src)[c4];
      float4 r0 = ((const float4*)rlds)[c4];
      float4 r1 = ((const float4*)rlds)[768 + c4];
      bf16x4 b;
      b[0] = (bf16)sv.x; b[1] = (bf16)sv.y; b[2] = (bf16)sv.z; b[3] = (bf16)sv.w;
      ((bf16x4*)d)[c4] = b;
      float f0 = (float)b[0], f1 = (float)b[1], f2 = (float)b[2], f3 = (float)b[3];
      a0 += f0 * f0 * (r0.x * r0.x) + f1 * f1 * (r0.y * r0.y)
          + f2 * f2 * (r0.z * r0.z) + f3 * f3 * (r0.w * r0.w);
      a1 += f0 * f0 * (r1.x * r1.x) + f1 * f1 * (r1.y * r1.y)
          + f2 * f2 * (r1.z * r1.z) + f3 * f3 * (r1.w * r1.w);
    }
    for (int o = 16; o; o >>= 1) { a0 += __shfl_xor(a0, o); a1 += __shfl_xor(a1, o); }
    if (l32 == 0) { A[rx] = a0 - 2.f * c0; A[S_N + rx] = a1 - 2.f * c1; }
  } else {
    bf16* d0 = V + (size_t)rx * F_N;
    bf16* d1 = V + ((size_t)X_N + rx) * F_N;
    const float* slds = rlds + 6144;
    float q0 = 0.f, q1 = 0.f;
#pragma unroll 4
    for (int k = 0; k < 24; ++k) {
      int c4 = l32 + k * 32;
      float4 xv = ((const float4*)src)[c4];
      float4 r0 = ((const float4*)rlds)[c4];
      float4 r1 = ((const float4*)rlds)[768 + c4];
      float4 s0 = ((const float4*)slds)[c4];
      float4 s1 = ((const float4*)slds)[768 + c4];
      bf16x4 y0, y1;
      y0[0] = (bf16)(xv.x * r0.x * r0.x); y0[1] = (bf16)(xv.y * r0.y * r0.y);
      y0[2] = (bf16)(xv.z * r0.z * r0.z); y0[3] = (bf16)(xv.w * r0.w * r0.w);
      y1[0] = (bf16)(xv.x * r1.x * r1.x); y1[1] = (bf16)(xv.y * r1.y * r1.y);
      y1[2] = (bf16)(xv.z * r1.z * r1.z); y1[3] = (bf16)(xv.w * r1.w * r1.w);
      ((bf16x4*)d0)[c4] = y0;
      ((bf16x4*)d1)[c4] = y1;
      float g0 = (float)y0[0] * s0.x, g1 = (float)y0[1] * s0.y;
      float g2 = (float)y0[2] * s0.z, g3 = (float)y0[3] * s0.w;
      q0 += g0 * g0 + g1 * g1 + g2 * g2 + g3 * g3;
      float h0 = (float)y1[0] * s1.x, h1 = (float)y1[1] * s1.y;
      float h2 = (float)y1[2] * s1.z, h3 = (float)y1[3] * s1.w;
      q1 += h0 * h0 + h1 * h1 + h2 * h2 + h3 * h3;
    }
    for (int o = 16; o; o >>= 1) { q0 += __shfl_xor(q0, o); q1 += __shfl_xor(q1, o); }
    if (l32 == 0) { C[rx] = q0; C[X_N + rx] = q1; }
  }
}

// ---------------- P1: logits[g,s,x] = (u v_g^T)[s,x] - 0.5*(A'[g,s]+C[g,x]) -
// R8/R11 core verbatim (measured best 53.7us): single barrier + counted
// vmcnt(6) per K-tile, consumption-ordered reads, ni-outer MFMA nest,
// setprio, flat 3-D grid, g-independent U.
__global__ __launch_bounds__(512, 2) void k_gemm(const bf16* __restrict__ U, const bf16* __restrict__ V,
                                                 const float* __restrict__ A, const float* __restrict__ C,
                                                 float* __restrict__ logits) {
  __shared__ i32x4 lds[NBUF * 2048 + NBUF * 1024];  // 144 KiB
  i32x4* ldsA = lds;
  i32x4* ldsB = lds + NBUF * 2048;

  int t = threadIdx.x;
  int g = blockIdx.z;
  int bm = blockIdx.y * TM;
  int bn = blockIdx.x * TN;

  const bf16* Ub = U + (size_t)bm * F_N;                      // g-independent
  const bf16* Vb = V + ((size_t)g * X_N + bn) * F_N;

  int wave = t >> 6, lane = t & 63;
  int pos = wave >> 1;
  int kh = wave & 1;
  int wm = pos >> 1;
  int wn = pos & 1;
  int r = lane & 15, q = lane >> 4;
  int fr = (r >> 1) & 7;
  int ck = (kh * 4 + q) ^ fr;
  int abase = (wm * 128 + r) * 8;
  int bbase = (wn * 64 + r) * 8;

  int row0 = t >> 3;
  int gcc = (t & 7) ^ ((t >> 4) & 7);
  const bf16* gA[4];
  const bf16* gB[2];
#pragma unroll
  for (int j = 0; j < 4; ++j) gA[j] = Ub + (size_t)(row0 + j * 64) * F_N + gcc * 8;
#pragma unroll
  for (int j = 0; j < 2; ++j) gB[j] = Vb + (size_t)(row0 + j * 64) * F_N + gcc * 8;

  f32x4 acc[8][4] = {};
  bf16x8 af[8], bfr[4];

#pragma unroll
  for (int j = 0; j < 4; ++j) gload_lds16(gA[j], &ldsA[0 * 2048 + t + j * 512]);
#pragma unroll
  for (int j = 0; j < 2; ++j) gload_lds16(gB[j], &ldsB[0 * 1024 + t + j * 512]);
#pragma unroll
  for (int j = 0; j < 4; ++j) gload_lds16(gA[j] + BK, &ldsA[1 * 2048 + t + j * 512]);
#pragma unroll
  for (int j = 0; j < 2; ++j) gload_lds16(gB[j] + BK, &ldsB[1 * 1024 + t + j * 512]);
  asm volatile("s_waitcnt vmcnt(6)" ::: "memory");
  __builtin_amdgcn_s_barrier();
  __builtin_amdgcn_sched_barrier(0);
#pragma unroll
  for (int ni = 0; ni < 4; ++ni)
    bfr[ni] = __builtin_bit_cast(bf16x8, ldsB[bbase + ni * 128 + ck]);
#pragma unroll
  for (int mi = 0; mi < 8; ++mi)
    af[mi] = __builtin_bit_cast(bf16x8, ldsA[abase + mi * 128 + ck]);

  int cur = 0;
  for (int it = 0; it < ITERS; ++it) {
    int k2 = it + 2;
    int pk = (k2 < ITERS ? k2 : 0) * BK;
    int stg = (cur >= 1) ? cur - 1 : 2;
    int nxt = (cur == 2) ? 0 : cur + 1;
    const i32x4* LAn = ldsA + nxt * 2048;
    const i32x4* LBn = ldsB + nxt * 1024;

    gload_lds16(gA[0] + pk, &ldsA[stg * 2048 + t]);
    gload_lds16(gA[1] + pk, &ldsA[stg * 2048 + t + 512]);
    gload_lds16(gA[2] + pk, &ldsA[stg * 2048 + t + 1024]);
    gload_lds16(gA[3] + pk, &ldsA[stg * 2048 + t + 1536]);
    gload_lds16(gB[0] + pk, &ldsB[stg * 1024 + t]);
    gload_lds16(gB[1] + pk, &ldsB[stg * 1024 + t + 512]);

    __builtin_amdgcn_s_setprio(1);
#pragma unroll
    for (int ni = 0; ni < 4; ++ni)
#pragma unroll
      for (int mi = 0; mi < 8; ++mi)
        acc[mi][ni] = __builtin_amdgcn_mfma_f32_16x16x32_bf16(af[mi], bfr[ni], acc[mi][ni], 0, 0, 0);
    __builtin_amdgcn_s_setprio(0);

    asm volatile("s_waitcnt vmcnt(6)" ::: "memory");
    __builtin_amdgcn_s_barrier();
    __builtin_amdgcn_sched_barrier(0);
#pragma unroll
    for (int ni = 0; ni < 4; ++ni)
      bfr[ni] = __builtin_bit_cast(bf16x8, LBn[bbase + ni * 128 + ck]);
#pragma unroll
    for (int mi = 0; mi < 8; ++mi)
      af[mi] = __builtin_bit_cast(bf16x8, LAn[abase + mi * 128 + ck]);

    cur = nxt;
  }

  asm volatile("s_waitcnt vmcnt(0) lgkmcnt(0)" ::: "memory");
  __builtin_amdgcn_s_barrier();

  // pair half-exchange: wave w and w^1 share one 128x64 output.
  f32x4* scr = (f32x4*)lds;
  {
    f32x4* mw = scr + wave * 1024;
    if (kh == 0) {
#pragma unroll
      for (int mi = 0; mi < 8; ++mi)
#pragma unroll
        for (int nl = 0; nl < 2; ++nl)
          mw[(mi * 2 + nl) * 64 + lane] = acc[mi][2 + nl];
    } else {
#pragma unroll
      for (int mi = 0; mi < 8; ++mi)
#pragma unroll
        for (int nl = 0; nl < 2; ++nl)
          mw[(mi * 2 + nl) * 64 + lane] = acc[mi][nl];
    }
  }
  __syncthreads();
  {
    const f32x4* pw = scr + (wave ^ 1) * 1024;
    if (kh == 0) {
#pragma unroll
      for (int mi = 0; mi < 8; ++mi)
#pragma unroll
        for (int nl = 0; nl < 2; ++nl)
          acc[mi][nl] += pw[(mi * 2 + nl) * 64 + lane];
    } else {
#pragma unroll
      for (int mi = 0; mi < 8; ++mi)
#pragma unroll
        for (int nl = 0; nl < 2; ++nl)
          acc[mi][2 + nl] += pw[(mi * 2 + nl) * 64 + lane];
    }
  }

  const float* Ap = A + (size_t)g * S_N + bm + wm * 128;
  const float* Cp = C + (size_t)g * X_N + bn + wn * 64 + kh * 32;
  float cv[2];
  cv[0] = Cp[r]; cv[1] = Cp[16 + r];
#pragma unroll
  for (int mi = 0; mi < 8; ++mi) {
#pragma unroll
    for (int i = 0; i < 4; ++i) {
      int rowl = mi * 16 + q * 4 + i;
      float av = Ap[rowl];
      float* orow = logits + ((size_t)g * S_N + bm + wm * 128 + rowl) * X_N + bn + wn * 64 + kh * 32;
      if (kh == 0) {
        orow[r]      = acc[mi][0][i] - 0.5f * (av + cv[0]);
        orow[16 + r] = acc[mi][1][i] - 0.5f * (av + cv[1]);
      } else {
        orow[r]      = acc[mi][2][i] - 0.5f * (av + cv[0]);
        orow[16 + r] = acc[mi][3][i] - 0.5f * (av + cv[1]);
      }
    }
  }
}

// ---------------- P2: out[s] = LSE over (g,x) of logits - log(X*G) ----------
// One wave per row (validated as R10's phase 2): 256 blocks x 512 thr,
// 8 rows/block, pure shfl_xor reduce — no block barrier, no LDS.
__global__ __launch_bounds__(512) void k_lse(const float* __restrict__ logits,
                                             float* __restrict__ out) {
  int t = threadIdx.x;
  int wv = t >> 6, l = t & 63;
  int s = blockIdx.x * 8 + wv;         // 0..2047
  const float4* p0 = (const float4*)(logits + (size_t)s * X_N);
  const float4* p1 = (const float4*)(logits + ((size_t)S_N + s) * X_N);
  float4 v[16];
#pragma unroll
  for (int k = 0; k < 8; ++k) { v[k] = p0[l + k * 64]; v[8 + k] = p1[l + k * 64]; }
  float m = v[0].x;
#pragma unroll
  for (int k = 0; k < 16; ++k) {
    m = fmaxf(m, v[k].x); m = fmaxf(m, v[k].y);
    m = fmaxf(m, v[k].z); m = fmaxf(m, v[k].w);
  }
  for (int o = 32; o; o >>= 1) m = fmaxf(m, __shfl_xor(m, o));
  float sum = 0.f;
#pragma unroll
  for (int k = 0; k < 16; ++k) {
    sum += expf(v[k].x - m) + expf(v[k].y - m) + expf(v[k].z - m) + expf(v[k].w - m);
  }
  for (int o = 32; o; o >>= 1) sum += __shfl_xor(sum, o);
  if (l == 0) out[s] = m + logf(sum) - 8.317766166719343f;  // log(4096)
}

extern "C" void kernel_launch(void* const* d_in, const int* in_sizes, int n_in,
                              void* d_out, int out_size, void* d_ws, size_t ws_size,
                              hipStream_t stream) {
  const float* samples = (const float*)d_in[0];  // [S, F] fp32
  const float* xin     = (const float*)d_in[1];  // [X, F] fp32
  const float* stdv    = (const float*)d_in[2];  // [G, F] fp32
  float* out = (float*)d_out;                    // [S] fp32

  char* ws = (char*)d_ws;
  size_t off = 0;
  bf16* U = (bf16*)(ws + off);        off += (size_t)S_N * F_N * 2;          // 12.6 MB (g-independent)
  bf16* V = (bf16*)(ws + off);        off += (size_t)G_N * X_N * F_N * 2;    // 25.2 MB
  float* logits = (float*)(ws + off); off += (size_t)G_N * S_N * X_N * 4;    // 33.6 MB
  float* A = (float*)(ws + off);      off += (size_t)G_N * S_N * 4;
  float* C = (float*)(ws + off);      off += (size_t)G_N * X_N * 4;

  k_prep<<<dim3(256), dim3(512), 0, stream>>>(samples, xin, stdv, U, V, A, C);
  k_gemm<<<dim3(X_N / TN, S_N / TM, G_N), dim3(512), 0, stream>>>(U, V, A, C, logits);
  k_lse<<<dim3(256), dim3(512), 0, stream>>>(logits, out);
}